// Round 4
// baseline (101.736 us; speedup 1.0000x reference)
//
#include <hip/hip_runtime.h>
#include <math.h>
#include <float.h>

// ChamferLoss: set1/set2 [8, 4096, 3] fp32 -> scalar
// out = sum of all 65536 per-point min distances / 2^27
//
// Round-4 structure: DB points are wave-uniform -> fetch via the SCALAR pipe
// (s_load_dwordx16, 4 packed points/inst) instead of LDS. v_fma_f32 takes the
// point component as its single SGPR operand; queries live in VGPRs.
// Inner cost: 1 v_mov(|p|^2) + 4 queries x (3 fma + 1 min) = 17 VALU / 4 pairs.
// A pre-pack kernel writes {x,y,z,|p|^2} (DB view) and {-2x,-2y,-2z,|q|^2}
// (query view) into d_ws so the hot loop is pure fma+min.

#define BATCH   8
#define NPTS    4096
#define NSET    (BATCH * NPTS)    // 32768 points per set
#define THREADS 1024
#define QB      256               // queries per block
#define QPT     4                 // queries per thread (lane)
#define NW      (THREADS / 64)    // 16 waves per block
#define PPW     (NPTS / NW)       // 256 points scanned per wave

// ws layout (float4): [0 .. 2*NSET)   P  = {x, y, z, ||p||^2}   (set1 then set2)
//                     [2*NSET .. 4*NSET) Qc = {-2x, -2y, -2z, ||q||^2}
__global__ __launch_bounds__(256)
void pack_points(const float* __restrict__ s1, const float* __restrict__ s2,
                 float4* __restrict__ ws)
{
    const int t   = blockIdx.x * 256 + threadIdx.x;  // 0..16383, 4 points each
    const int set = t >> 13;                         // 0: set1, 1: set2
    const int tp  = t & 8191;                        // thread within set
    const float* __restrict__ src = set ? s2 : s1;

    const float4* g4 = (const float4*)src;
    const float4 r0 = g4[3 * tp + 0];
    const float4 r1 = g4[3 * tp + 1];
    const float4 r2 = g4[3 * tp + 2];

    float px[4] = {r0.x, r0.w, r1.z, r2.y};
    float py[4] = {r0.y, r1.x, r1.w, r2.z};
    float pz[4] = {r0.z, r1.y, r2.x, r2.w};

    const int base = set * NSET + 4 * tp;
    #pragma unroll
    for (int k = 0; k < 4; ++k) {
        const float n = fmaf(px[k], px[k], fmaf(py[k], py[k], pz[k] * pz[k]));
        ws[base + k]            = make_float4(px[k], py[k], pz[k], n);
        ws[2 * NSET + base + k] = make_float4(-2.0f * px[k], -2.0f * py[k],
                                              -2.0f * pz[k], n);
    }
}

__global__ __launch_bounds__(THREADS, 4)
void chamfer_main(const float4* __restrict__ ws, float* __restrict__ out)
{
    __shared__ float part[NW][QB];        // 16 KB partial mins

    const int blk = blockIdx.x;           // 0..255
    const int dir = blk >> 7;             // 0: set1->set2, 1: set2->set1
    const int b   = (blk >> 4) & 7;       // batch
    const int qb  = blk & 15;             // query block

    // DB = the OTHER set; queries = this direction's set (coeff view)
    const float4* __restrict__ P  = ws + ((dir ^ 1) * BATCH + b) * NPTS;
    const float4* __restrict__ Qc = ws + 2 * NSET + (dir * BATCH + b) * NPTS + qb * QB;

    const int t = threadIdx.x;
    const int l = t & 63;                                       // lane
    const int w = __builtin_amdgcn_readfirstlane(t >> 6);       // wave 0..15 (uniform)

    // --- this lane's 4 query coefficient sets (coalesced dwordx4 loads) ---
    float qa[QPT], qbv[QPT], qcv[QPT], dmin[QPT];
    #pragma unroll
    for (int j = 0; j < QPT; ++j) {
        const float4 q = Qc[j * 64 + l];
        qa[j] = q.x; qbv[j] = q.y; qcv[j] = q.z;
        dmin[j] = FLT_MAX;
    }

    // --- scan this wave's 256-point slice via scalar loads ---
    const float4* __restrict__ S = P + w * PPW;   // wave-uniform base

    #pragma unroll 2
    for (int c = 0; c < PPW; c += 4) {
        const float4 P0 = S[c + 0];
        const float4 P1 = S[c + 1];
        const float4 P2 = S[c + 2];
        const float4 P3 = S[c + 3];
        #pragma unroll
        for (int j = 0; j < QPT; ++j) {
            const float a = qa[j], bb = qbv[j], cc = qcv[j];
            const float d0 = fmaf(a, P0.x, fmaf(bb, P0.y, fmaf(cc, P0.z, P0.w)));
            const float d1 = fmaf(a, P1.x, fmaf(bb, P1.y, fmaf(cc, P1.z, P1.w)));
            const float d2 = fmaf(a, P2.x, fmaf(bb, P2.y, fmaf(cc, P2.z, P2.w)));
            const float d3 = fmaf(a, P3.x, fmaf(bb, P3.y, fmaf(cc, P3.z, P3.w)));
            dmin[j] = fminf(dmin[j], fminf(fminf(d0, d1), fminf(d2, d3)));
        }
    }

    // --- per-wave partials to LDS ---
    #pragma unroll
    for (int j = 0; j < QPT; ++j)
        part[w][j * 64 + l] = dmin[j];
    __syncthreads();

    // --- combine waves, finish d = sqrt(max(|q|^2 + m, 0)), reduce, atomic ---
    if (t < QB) {                         // waves 0..3, fully active
        float m = part[0][t];
        #pragma unroll
        for (int ww = 1; ww < NW; ++ww)
            m = fminf(m, part[ww][t]);
        const float qw = Qc[t].w;         // ||q||^2 (query index qb*QB + t)
        float dist = sqrtf(fmaxf(qw + m, 0.0f));

        #pragma unroll
        for (int off = 32; off > 0; off >>= 1)
            dist += __shfl_down(dist, off);
        if ((t & 63) == 0)
            atomicAdd(out, dist * (1.0f / 134217728.0f));   // 2^-27
    }
}

extern "C" void kernel_launch(void* const* d_in, const int* in_sizes, int n_in,
                              void* d_out, int out_size, void* d_ws, size_t ws_size,
                              hipStream_t stream) {
    const float* s1 = (const float*)d_in[0];
    const float* s2 = (const float*)d_in[1];
    float* out = (float*)d_out;
    float4* ws = (float4*)d_ws;           // needs 4*NSET*16 B = 2 MB

    hipMemsetAsync(out, 0, sizeof(float), stream);          // d_out poisoned 0xAA
    pack_points<<<dim3(64), dim3(256), 0, stream>>>(s1, s2, ws);
    chamfer_main<<<dim3(256), dim3(THREADS), 0, stream>>>(ws, out);
}

// Round 5
// 92.663 us; speedup vs baseline: 1.0979x; 1.0979x over previous
//
#include <hip/hip_runtime.h>
#include <math.h>
#include <float.h>

// ChamferLoss: set1/set2 [8, 4096, 3] fp32 -> scalar
// out = sum of all 65536 per-point min distances / 2^27
//
// Structure (R5):
//  - pack_points: ws <- P view {x,y,z,|p|^2} and Qc view {-2x,-2y,-2z,|q|^2};
//    also inits the qmin table to +inf bits.
//  - chamfer_main: 1024 blocks x 256 threads. Block = (dir, batch, qtile-512,
//    dbslice-512); each wave scans 128 points via WAVE-UNIFORM scalar loads
//    (s_load, points live in SGPRs), 8 queries/lane in VGPRs.
//    4.125 VALU insts/pair. Partial mins combined in LDS, then global
//    atomicMin on d^2 bits (uint order == float order for d^2 >= 0).
//  - finish: 65536 d^2 -> sqrt -> sum -> scaled atomicAdd.

#define BATCH 8
#define NPTS  4096
#define NSET  (BATCH * NPTS)     // 32768 points per set
#define QPT   8                  // queries per lane
#define QTILE 512                // queries per block (64 lanes * QPT)
#define SLICE 512                // DB points per block (128 per wave)

// ws layout (float4 units): [0, 2*NSET)       P   {x,y,z,|p|^2}, set1 then set2
//                           [2*NSET, 4*NSET)  Qc  {-2x,-2y,-2z,|q|^2}
//                           byte offset 4*NSET*16: qmin[2*NSET] uints (256 KB)

__global__ __launch_bounds__(256)
void pack_points(const float* __restrict__ s1, const float* __restrict__ s2,
                 float4* __restrict__ ws, unsigned int* __restrict__ qmin)
{
    const int t   = blockIdx.x * 256 + threadIdx.x;  // 0..16383, 4 points each
    const int set = t >> 13;
    const int tp  = t & 8191;
    const float* __restrict__ src = set ? s2 : s1;

    const float4* g4 = (const float4*)src;
    const float4 r0 = g4[3 * tp + 0];
    const float4 r1 = g4[3 * tp + 1];
    const float4 r2 = g4[3 * tp + 2];

    const float px[4] = {r0.x, r0.w, r1.z, r2.y};
    const float py[4] = {r0.y, r1.x, r1.w, r2.z};
    const float pz[4] = {r0.z, r1.y, r2.x, r2.w};

    const int base = set * NSET + 4 * tp;
    #pragma unroll
    for (int k = 0; k < 4; ++k) {
        const float n = fmaf(px[k], px[k], fmaf(py[k], py[k], pz[k] * pz[k]));
        ws[base + k]            = make_float4(px[k], py[k], pz[k], n);
        ws[2 * NSET + base + k] = make_float4(-2.0f * px[k], -2.0f * py[k],
                                              -2.0f * pz[k], n);
        qmin[base + k] = 0x7F800000u;    // +inf bits
    }
}

__global__ __launch_bounds__(256, 4)
void chamfer_main(const float4* __restrict__ Pall, const float4* __restrict__ Qall,
                  unsigned int* __restrict__ qmin)
{
    __shared__ float part[4][QTILE];     // 8 KB

    const int blk = blockIdx.x;          // 0..1023
    const int dir = blk >> 9;            // 0: set1->set2, 1: set2->set1
    const int b   = (blk >> 6) & 7;      // batch
    const int qt  = (blk >> 3) & 7;      // query tile (512 queries)
    const int sl  = blk & 7;             // DB slice (512 points)

    const float4* __restrict__ P  = Pall + ((dir ^ 1) * BATCH + b) * NPTS;
    const float4* __restrict__ Qc = Qall + (dir * BATCH + b) * NPTS + qt * QTILE;

    const int t = threadIdx.x;
    const int l = t & 63;
    const int w = t >> 6;                // wave 0..3

    // --- this lane's 8 query coefficient sets (coalesced, L2-hot) ---
    float qa[QPT], qb_[QPT], qc_[QPT], dmin[QPT];
    #pragma unroll
    for (int j = 0; j < QPT; ++j) {
        const float4 q = Qc[j * 64 + l];
        qa[j] = q.x; qb_[j] = q.y; qc_[j] = q.z;
        dmin[j] = FLT_MAX;
    }

    // --- wave-uniform DB slice base -> scalar loads ---
    const int sbase = __builtin_amdgcn_readfirstlane(sl * SLICE + w * (SLICE / 4));
    const float4* __restrict__ S = P + sbase;

    auto body = [&](const float4& P0, const float4& P1,
                    const float4& P2, const float4& P3) {
        #pragma unroll
        for (int j = 0; j < QPT; ++j) {
            const float a = qa[j], bb = qb_[j], cc = qc_[j];
            const float d0 = fmaf(a, P0.x, fmaf(bb, P0.y, fmaf(cc, P0.z, P0.w)));
            const float d1 = fmaf(a, P1.x, fmaf(bb, P1.y, fmaf(cc, P1.z, P1.w)));
            const float d2 = fmaf(a, P2.x, fmaf(bb, P2.y, fmaf(cc, P2.z, P2.w)));
            const float d3 = fmaf(a, P3.x, fmaf(bb, P3.y, fmaf(cc, P3.z, P3.w)));
            dmin[j] = fminf(dmin[j], fminf(fminf(d0, d1), fminf(d2, d3)));
        }
    };

    // software-pipelined: prefetch chunk c+1 while computing chunk c
    float4 A0 = S[0], A1 = S[1], A2 = S[2], A3 = S[3];
    for (int c = 0; c < (SLICE / 4) / 4 - 1; ++c) {       // 31 iterations
        const float4 B0 = S[4 * c + 4];
        const float4 B1 = S[4 * c + 5];
        const float4 B2 = S[4 * c + 6];
        const float4 B3 = S[4 * c + 7];
        body(A0, A1, A2, A3);
        A0 = B0; A1 = B1; A2 = B2; A3 = B3;
    }
    body(A0, A1, A2, A3);

    // --- LDS combine across the 4 waves ---
    #pragma unroll
    for (int j = 0; j < QPT; ++j)
        part[w][j * 64 + l] = dmin[j];
    __syncthreads();

    const int gqbase = (dir * BATCH + b) * NPTS + qt * QTILE;
    #pragma unroll
    for (int s = t; s < QTILE; s += 256) {
        const float m = fminf(fminf(part[0][s], part[1][s]),
                              fminf(part[2][s], part[3][s]));
        const float d2 = fmaxf(Qc[s].w + m, 0.0f);        // true squared distance
        atomicMin(&qmin[gqbase + s], __float_as_uint(d2));
    }
}

__global__ __launch_bounds__(256)
void finish(const unsigned int* __restrict__ qmin, float* __restrict__ out)
{
    const int t = blockIdx.x * 256 + threadIdx.x;         // 0..16383
    const uint4 v = ((const uint4*)qmin)[t];
    float s = sqrtf(__uint_as_float(v.x)) + sqrtf(__uint_as_float(v.y))
            + sqrtf(__uint_as_float(v.z)) + sqrtf(__uint_as_float(v.w));
    #pragma unroll
    for (int off = 32; off > 0; off >>= 1)
        s += __shfl_down(s, off);
    if ((threadIdx.x & 63) == 0)
        atomicAdd(out, s * (1.0f / 134217728.0f));        // 2^-27
}

extern "C" void kernel_launch(void* const* d_in, const int* in_sizes, int n_in,
                              void* d_out, int out_size, void* d_ws, size_t ws_size,
                              hipStream_t stream) {
    const float* s1 = (const float*)d_in[0];
    const float* s2 = (const float*)d_in[1];
    float* out = (float*)d_out;
    float4* ws = (float4*)d_ws;
    unsigned int* qmin = (unsigned int*)((char*)d_ws + (size_t)4 * NSET * 16);

    hipMemsetAsync(out, 0, sizeof(float), stream);
    pack_points<<<dim3(64),   dim3(256), 0, stream>>>(s1, s2, ws, qmin);
    chamfer_main<<<dim3(1024), dim3(256), 0, stream>>>(ws, ws + 2 * NSET, qmin);
    finish<<<dim3(64),        dim3(256), 0, stream>>>(qmin, out);
}